// Round 7
// baseline (243.461 us; speedup 1.0000x reference)
//
#include <hip/hip_runtime.h>
#include <math.h>
#include <stdint.h>

// Problem constants
#define D 768
#define S 2048
#define B_ 2
#define NROWS 4096   // B_*S
#define H 12
#define HD 64
#define R_ 16

typedef _Float16 half_t;
typedef _Float16 half8 __attribute__((ext_vector_type(8)));
typedef _Float16 half4 __attribute__((ext_vector_type(4)));
typedef float floatx4 __attribute__((ext_vector_type(4)));

#define MFMA32(a, b, c) __builtin_amdgcn_mfma_f32_16x16x32_f16(a, b, c, 0, 0, 0)
#define MFMA16(a, b, c) __builtin_amdgcn_mfma_f32_16x16x16f16(a, b, c, 0, 0, 0)
#define EXP2F(x) __builtin_amdgcn_exp2f(x)

// global -> LDS async DMA, 16B per lane; lane i lands at base + 16*i.
__device__ __forceinline__ void gl_lds16(const void* gp, half_t* lp) {
  __builtin_amdgcn_global_load_lds(
      (const __attribute__((address_space(1))) void*)(gp),
      (__attribute__((address_space(3))) void*)(lp), 16, 0, 0);
}

// ---------------------------------------------------------------------------
// Prep: build folded LoRA weights only (conversion now fused into QKV GEMM).
// Mh[j][k] = W[j][k] + 4*sum_r A[k,r]A[j,r]  (fp16, [j][k]). grid.y = q,k,v,o.
// ---------------------------------------------------------------------------
__global__ __launch_bounds__(256) void build_M4_kernel(
    const float* __restrict__ Wq, const float* __restrict__ Aq,
    const float* __restrict__ Wk, const float* __restrict__ Ak,
    const float* __restrict__ Wv, const float* __restrict__ Av,
    const float* __restrict__ Wo, half_t* __restrict__ Mq,
    half_t* __restrict__ Mk, half_t* __restrict__ Mv,
    half_t* __restrict__ Mo) {
  const int y = blockIdx.y;
  const float* W = (y == 0) ? Wq : (y == 1) ? Wk : (y == 2) ? Wv : Wo;
  const float* A = (y == 0) ? Aq : (y == 1) ? Ak : (y == 2) ? Av : nullptr;
  half_t* M = (y == 0) ? Mq : (y == 1) ? Mk : (y == 2) ? Mv : Mo;
  int idx = blockIdx.x * 256 + threadIdx.x;  // j*768 + k
  int j = idx / D;
  int kk = idx - j * D;
  float acc = W[idx];
  if (A != nullptr) {
    float s = 0.f;
#pragma unroll
    for (int r = 0; r < R_; ++r) s += A[kk * R_ + r] * A[j * R_ + r];
    acc += 4.0f * s;
  }
  M[idx] = (half_t)acc;
}

// ---------------------------------------------------------------------------
// QKV GEMM with fused fp32->fp16 convert on the A operand.
// C[n][j] = sum_k X[n][k] * Mh[j][k] + bias[j];  X is fp32 (original input).
// 128x128 tile, BK=64, 256 thr (4 waves, 2x2). A: fp32 global->regs->cvt->
// ds_write (one stage in flight). B: DMA prefetch. One barrier per iter.
// z==2 writes V output TRANSPOSED per head: vt[(b*H+h)*HD+d][s].
// ---------------------------------------------------------------------------
__global__ __launch_bounds__(256) void gemm_qkv_kernel(
    const float* __restrict__ x0, const float* __restrict__ x1,
    const float* __restrict__ x2, const half_t* __restrict__ m0,
    const half_t* __restrict__ m1, const half_t* __restrict__ m2,
    const float* __restrict__ b0, const float* __restrict__ b1,
    const float* __restrict__ b2, half_t* __restrict__ o0,
    half_t* __restrict__ o1, half_t* __restrict__ o2) {
  constexpr int PB = 32 * 512;  // halfs per buffer: 16 A-groups + 16 B-groups
  constexpr int TRS = 136;      // V-transpose LDS stride (halfs)
  __shared__ __align__(16) half_t smem[2 * PB];  // 64KB

  const int z = blockIdx.z;
  const float* X = (z == 0) ? x0 : (z == 1) ? x1 : x2;
  const half_t* M = (z == 0) ? m0 : (z == 1) ? m1 : m2;
  const float* bias = (z == 0) ? b0 : (z == 1) ? b1 : b2;
  half_t* Out = (z == 0) ? o0 : (z == 1) ? o1 : o2;

  const int tid = threadIdx.x;
  const int lane = tid & 63;
  const int wv = tid >> 6;
  const int lr = lane & 15;
  const int lq = lane >> 4;
  const int row0 = blockIdx.y * 128;
  const int j0 = blockIdx.x * 128;
  const int wr = wv >> 1;
  const int wc = wv & 1;

  // A-staging slice for this thread: group g = tid>>4, sub a = tid&15.
  // Covers lanes 4a..4a+3 of group g: rows arow0+i, k chunk acolb (+k0).
  const int g_ = tid >> 4;
  const int a_ = tid & 15;
  const int arow0 = row0 + (g_ >> 1) * 16 + (a_ & 3) * 4;
  const int acolb = (g_ & 1) * 32 + (a_ >> 2) * 8;

  floatx4 acc[4][4] = {};
  float4 ra[8];

#define LOADA(k0)                                                              \
  do {                                                                         \
    _Pragma("unroll") for (int i = 0; i < 4; ++i) {                            \
      const float* p = X + (size_t)(arow0 + i) * D + (k0) + acolb;             \
      ra[2 * i] = *reinterpret_cast<const float4*>(p);                         \
      ra[2 * i + 1] = *reinterpret_cast<const float4*>(p + 4);                 \
    }                                                                          \
  } while (0)

#define WRITEA(bufi)                                                           \
  do {                                                                         \
    _Pragma("unroll") for (int i = 0; i < 4; ++i) {                            \
      half8 hh;                                                                \
      hh[0] = (half_t)ra[2 * i].x;                                             \
      hh[1] = (half_t)ra[2 * i].y;                                             \
      hh[2] = (half_t)ra[2 * i].z;                                             \
      hh[3] = (half_t)ra[2 * i].w;                                             \
      hh[4] = (half_t)ra[2 * i + 1].x;                                         \
      hh[5] = (half_t)ra[2 * i + 1].y;                                         \
      hh[6] = (half_t)ra[2 * i + 1].z;                                         \
      hh[7] = (half_t)ra[2 * i + 1].w;                                         \
      *reinterpret_cast<half8*>(smem + (bufi)*PB + 32 * tid + 8 * i) = hh;     \
    }                                                                          \
  } while (0)

#define STAGEB(bufi, k0)                                                       \
  do {                                                                         \
    _Pragma("unroll") for (int gi = 0; gi < 4; ++gi) {                         \
      int gb = wv * 4 + gi;                                                    \
      int u = gb >> 1, cb = gb & 1;                                            \
      gl_lds16(M + (size_t)(j0 + u * 16 + lr) * D + (k0) + cb * 32 + lq * 8,   \
               smem + (bufi)*PB + 16 * 512 + gb * 512);                        \
    }                                                                          \
  } while (0)

  // prologue
  STAGEB(0, 0);
  LOADA(0);
  WRITEA(0);
  __syncthreads();

  for (int it = 0; it < D / 64; ++it) {
    const int cur = it & 1;
    if (it + 1 < D / 64) {
      STAGEB(cur ^ 1, (it + 1) * 64);
      LOADA((it + 1) * 64);
    }
    const half_t* Ab = smem + cur * PB;
    const half_t* Bb = Ab + 16 * 512;
#pragma unroll
    for (int c = 0; c < 2; ++c) {
      half8 af[4], bf[4];
#pragma unroll
      for (int t = 0; t < 4; ++t)
        af[t] = *reinterpret_cast<const half8*>(
            &Ab[(((wr * 4 + t) * 2 + c) * 64 + lane) * 8]);
#pragma unroll
      for (int u = 0; u < 4; ++u)
        bf[u] = *reinterpret_cast<const half8*>(
            &Bb[(((wc * 4 + u) * 2 + c) * 64 + lane) * 8]);
#pragma unroll
      for (int t = 0; t < 4; ++t)
#pragma unroll
        for (int u = 0; u < 4; ++u) acc[t][u] = MFMA32(af[t], bf[u], acc[t][u]);
    }
    if (it + 1 < D / 64) WRITEA(cur ^ 1);
    __syncthreads();
  }
#undef LOADA
#undef WRITEA
#undef STAGEB

  float bv[4];
#pragma unroll
  for (int u = 0; u < 4; ++u) bv[u] = bias[j0 + (wc * 4 + u) * 16 + lr];

  if (z == 2) {
    // transpose through LDS, emit V^T [b][h][d][S] coalesced
#pragma unroll
    for (int t = 0; t < 4; ++t) {
#pragma unroll
      for (int u = 0; u < 4; ++u) {
        int c_local = (wc * 4 + u) * 16 + lr;
#pragma unroll
        for (int r = 0; r < 4; ++r) {
          int r_local = (wr * 4 + t) * 16 + lq * 4 + r;
          smem[c_local * TRS + r_local] = (half_t)(acc[t][u][r] + bv[u]);
        }
      }
    }
    __syncthreads();
    const int bb = row0 >> 11;
    const int s_base = row0 & 2047;
#pragma unroll
    for (int it = 0; it < 8; ++it) {
      int unit = it * 256 + tid;       // 0..2047
      int c_local = unit >> 4;         // channel 0..127
      int chunk = unit & 15;           // token chunk
      half8 vv =
          *reinterpret_cast<const half8*>(&smem[c_local * TRS + chunk * 8]);
      int gc = j0 + c_local;
      int hh = gc >> 6, dd = gc & 63;
      *reinterpret_cast<half8*>(
          &Out[((size_t)(bb * H + hh) * HD + dd) * S + s_base + chunk * 8]) = vv;
    }
    return;
  }

#pragma unroll
  for (int t = 0; t < 4; ++t) {
#pragma unroll
    for (int u = 0; u < 4; ++u) {
#pragma unroll
      for (int r = 0; r < 4; ++r) {
        int gr = row0 + (wr * 4 + t) * 16 + lq * 4 + r;
        int gc = j0 + (wc * 4 + u) * 16 + lr;
        Out[(size_t)gr * D + gc] = (half_t)(acc[t][u][r] + bv[u]);
      }
    }
  }
}

// ---------------------------------------------------------------------------
// Out-projection GEMM (fp16 in, fp32 out): 64x128 tile, 4 waves (1x4),
// both operands DMA-prefetched, one barrier per iter.
// ---------------------------------------------------------------------------
__global__ __launch_bounds__(256) void gemm_o_kernel(
    const half_t* __restrict__ Xh, const half_t* __restrict__ M,
    const float* __restrict__ bias, float* __restrict__ Out) {
  constexpr int AG = 8;           // A groups (64 rows)
  constexpr int G = AG + 16;      // 24 groups
  constexpr int PB = G * 512;     // halfs per buffer (24KB)
  __shared__ __align__(16) half_t smem[2 * PB];  // 48KB

  const int tid = threadIdx.x;
  const int lane = tid & 63;
  const int wv = tid >> 6;
  const int lr = lane & 15;
  const int lq = lane >> 4;
  const int row0 = blockIdx.y * 64;
  const int j0 = blockIdx.x * 128;
  const int wc = wv;  // 1x4 wave grid

  floatx4 acc[4][2] = {};

#define GSTAGE(bufi, k0)                                                       \
  do {                                                                         \
    _Pragma("unroll") for (int gi = 0; gi < 6; ++gi) {                         \
      int g = wv * 6 + gi;                                                     \
      if (g < AG) {                                                            \
        int t = g >> 1, c = g & 1;                                             \
        gl_lds16(                                                              \
            Xh + (size_t)(row0 + t * 16 + lr) * D + (k0) + c * 32 + lq * 8,    \
            smem + (bufi)*PB + g * 512);                                       \
      } else {                                                                 \
        int g2 = g - AG;                                                       \
        int u = g2 >> 1, c = g2 & 1;                                           \
        gl_lds16(                                                              \
            M + (size_t)(j0 + u * 16 + lr) * D + (k0) + c * 32 + lq * 8,       \
            smem + (bufi)*PB + AG * 512 + g2 * 512);                           \
      }                                                                        \
    }                                                                          \
  } while (0)

  GSTAGE(0, 0);
  __syncthreads();

  for (int it = 0; it < D / 64; ++it) {
    const int cur = it & 1;
    if (it + 1 < D / 64) GSTAGE(cur ^ 1, (it + 1) * 64);
    const half_t* Ab = smem + cur * PB;
    const half_t* Bb = Ab + AG * 512;
#pragma unroll
    for (int c = 0; c < 2; ++c) {
      half8 af[4], bf[2];
#pragma unroll
      for (int t = 0; t < 4; ++t)
        af[t] = *reinterpret_cast<const half8*>(
            &Ab[((t * 2 + c) * 64 + lane) * 8]);
#pragma unroll
      for (int u = 0; u < 2; ++u)
        bf[u] = *reinterpret_cast<const half8*>(
            &Bb[(((wc * 2 + u) * 2 + c) * 64 + lane) * 8]);
#pragma unroll
      for (int t = 0; t < 4; ++t)
#pragma unroll
        for (int u = 0; u < 2; ++u) acc[t][u] = MFMA32(af[t], bf[u], acc[t][u]);
    }
    __syncthreads();
  }
#undef GSTAGE

  float bv[2];
#pragma unroll
  for (int u = 0; u < 2; ++u) bv[u] = bias[j0 + (wc * 2 + u) * 16 + lr];
#pragma unroll
  for (int t = 0; t < 4; ++t) {
#pragma unroll
    for (int u = 0; u < 2; ++u) {
#pragma unroll
      for (int r = 0; r < 4; ++r) {
        int gr = row0 + t * 16 + lq * 4 + r;
        int gc = j0 + (wc * 2 + u) * 16 + lr;
        Out[(size_t)gr * D + gc] = acc[t][u][r] + bv[u];
      }
    }
  }
}

// ---------------------------------------------------------------------------
// Flash attention, in-block split-K. 512 threads (8 waves), 64 q-rows/block.
// Wave w: q-subtile t=w&3 (16 rows), k'-half = w>>2 (2 of 4 u-tiles per iter).
// Partials are additive (no running max) -> merged once at the end via LDS.
//   - S^T = K*Q^T: C-layout == A-frag layout of 16x16x16 -> P in registers.
//   - exp2 (v_exp_f32) with 0.125*log2e folded into Q scale.
//   - l via ones-MFMA: ol[r] = row-sum of P, reg-aligned with o (no shuffles).
// ---------------------------------------------------------------------------
__global__ __launch_bounds__(512, 6) void attn_mfma_kernel(
    const half_t* __restrict__ Qh, const half_t* __restrict__ Kh,
    const half_t* __restrict__ Vt_g, half_t* __restrict__ Oh) {
  __shared__ __align__(16) half_t smem[16384];  // 32KB: Ks[2][4k] Vs[2][4k]
  half_t* Ks = smem;           // [2][8*512]
  half_t* Vs = smem + 8192;    // [2][8*512]

  const int tid = threadIdx.x;
  const int lane = tid & 63;
  const int wv = tid >> 6;       // 0..7
  const int t_ = wv & 3;         // q-subtile
  const int half_ = wv >> 2;     // k'-half
  const int lr = lane & 15;
  const int lq = lane >> 4;
  const int q0 = blockIdx.x * 64;
  const int h = blockIdx.y;
  const int b = blockIdx.z;
  const size_t base = (size_t)b * S * D + h * HD;              // + row*D
  const size_t vtbase = (size_t)(b * H + h) * HD * (size_t)S;  // + d*S + s
  const int qw = q0 + t_ * 16;

  // Q B-fragments, scale = (1/8)*log2(e) -> exp2 later
  const half_t qscale = (half_t)0.18033688f;
  half8 qf[2];
#pragma unroll
  for (int c = 0; c < 2; ++c) {
    half8 qv = *reinterpret_cast<const half8*>(
        &Qh[base + (size_t)(qw + lr) * D + c * 32 + lq * 8]);
#pragma unroll
    for (int j = 0; j < 8; ++j) qv[j] = qv[j] * qscale;
    qf[c] = qv;
  }

  half4 ones;
#pragma unroll
  for (int j = 0; j < 4; ++j) ones[j] = (half_t)1.0f;

  floatx4 o[4] = {};
  floatx4 ol = {};

  // 16 DMA groups (8 K + 8 V), 2 per wave
#define STAGE(bufi, kb)                                                        \
  do {                                                                         \
    _Pragma("unroll") for (int gi = 0; gi < 2; ++gi) {                         \
      int g = wv * 2 + gi;                                                     \
      if (g < 8) {                                                             \
        int u = g >> 1, c = g & 1;                                             \
        gl_lds16(                                                              \
            Kh + base + (size_t)((kb) + u * 16 + lr) * D + c * 32 + lq * 8,    \
            Ks + (bufi)*4096 + g * 512);                                       \
      } else {                                                                 \
        int gv = g - 8;                                                        \
        int ud = gv >> 1, c = gv & 1;                                          \
        gl_lds16(                                                              \
            Vt_g + vtbase + (size_t)(ud * 16 + lr) * S + (kb) + c * 32 +       \
                lq * 8,                                                        \
            Vs + (bufi)*4096 + gv * 512);                                      \
      }                                                                        \
    }                                                                          \
  } while (0)

  STAGE(0, 0);
  __syncthreads();

  for (int it = 0; it < S / 64; ++it) {
    const int cur = it & 1;
    if (it + 1 < S / 64) STAGE(cur ^ 1, (it + 1) * 64);

#pragma unroll
    for (int ui = 0; ui < 2; ++ui) {
      const int u = half_ * 2 + ui;
      half8 kf0 = *reinterpret_cast<const half8*>(
          &Ks[cur * 4096 + ((u * 2 + 0) * 64 + lane) * 8]);
      half8 kf1 = *reinterpret_cast<const half8*>(
          &Ks[cur * 4096 + ((u * 2 + 1) * 64 + lane) * 8]);
      floatx4 st = {};
      st = MFMA32(kf0, qf[0], st);
      st = MFMA32(kf1, qf[1], st);
      half4 pf;
      pf[0] = (half_t)EXP2F(st[0]);
      pf[1] = (half_t)EXP2F(st[1]);
      pf[2] = (half_t)EXP2F(st[2]);
      pf[3] = (half_t)EXP2F(st[3]);
#pragma unroll
      for (int ud = 0; ud < 4; ++ud) {
        half4 vf = *reinterpret_cast<const half4*>(
            &Vs[cur * 4096 + ((ud * 2 + (u >> 1)) * 64 +
                              ((((u & 1) * 2) + (lq >> 1)) * 16 + lr)) *
                                 8 +
                (lq & 1) * 4]);
        o[ud] = MFMA16(pf, vf, o[ud]);
      }
      ol = MFMA16(pf, ones, ol);  // row-sums -> l, reg-aligned with o
    }
    __syncthreads();
  }
#undef STAGE

  // merge k'-halves: waves 4-7 deposit partials (SoA, stride 260), 0-3 reduce
  float* red = (float*)smem;  // 20 comps x 260 floats = 20.8KB <= 32KB
  const int slot = t_ * 64 + lane;  // 0..255
  if (half_ == 1) {
#pragma unroll
    for (int comp = 0; comp < 16; ++comp)
      red[comp * 260 + slot] = o[comp >> 2][comp & 3];
#pragma unroll
    for (int r = 0; r < 4; ++r) red[(16 + r) * 260 + slot] = ol[r];
  }
  __syncthreads();
  if (half_ == 0) {
#pragma unroll
    for (int comp = 0; comp < 16; ++comp)
      o[comp >> 2][comp & 3] += red[comp * 260 + slot];
    float linv[4];
#pragma unroll
    for (int r = 0; r < 4; ++r)
      linv[r] = 1.0f / (ol[r] + red[(16 + r) * 260 + slot]);
#pragma unroll
    for (int ud = 0; ud < 4; ++ud) {
#pragma unroll
      for (int r = 0; r < 4; ++r) {
        int row = qw + lq * 4 + r;
        int col = h * HD + ud * 16 + lr;
        Oh[(size_t)(b * S + row) * D + col] = (half_t)(o[ud][r] * linv[r]);
      }
    }
  }
}

// ---------------------------------------------------------------------------
// Launch
// ---------------------------------------------------------------------------
extern "C" void kernel_launch(void* const* d_in, const int* in_sizes, int n_in,
                              void* d_out, int out_size, void* d_ws,
                              size_t ws_size, hipStream_t stream) {
  const float* query = (const float*)d_in[0];
  const float* key   = (const float*)d_in[1];
  const float* value = (const float*)d_in[2];
  const float* Wq = (const float*)d_in[3];
  const float* bq = (const float*)d_in[4];
  const float* Aq = (const float*)d_in[5];
  const float* Wk = (const float*)d_in[6];
  const float* bk = (const float*)d_in[7];
  const float* Ak = (const float*)d_in[8];
  const float* Wv = (const float*)d_in[9];
  const float* bv = (const float*)d_in[10];
  const float* Av = (const float*)d_in[11];
  const float* Wo = (const float*)d_in[12];
  const float* bo = (const float*)d_in[13];
  float* out = (float*)d_out;

  half_t* hw = (half_t*)d_ws;
  const size_t XSZ = (size_t)NROWS * D;  // 3145728
  const size_t MSZ = (size_t)D * D;      // 589824
  half_t* qh = hw;              // Q projection [n][D]
  half_t* kh = qh + XSZ;        // K projection [n][D]
  half_t* vt = kh + XSZ;        // V projection TRANSPOSED [b][h][d][S]
  half_t* ab = vt + XSZ;        // attention output [n][D]
  half_t* Mq = ab + XSZ;
  half_t* Mk = Mq + MSZ;
  half_t* Mv = Mk + MSZ;
  half_t* Mo = Mv + MSZ;

  dim3 gm(D * D / 256, 4);  // (2304, 4)
  build_M4_kernel<<<gm, 256, 0, stream>>>(Wq, Aq, Wk, Ak, Wv, Av, Wo, Mq, Mk,
                                          Mv, Mo);

  dim3 gq(D / 128, NROWS / 128, 3);  // (6, 32, 3)
  gemm_qkv_kernel<<<gq, 256, 0, stream>>>(query, key, value, Mq, Mk, Mv, bq,
                                          bk, bv, qh, kh, vt);

  dim3 ga(S / 64, H, B_);  // (32, 12, 2)
  attn_mfma_kernel<<<ga, 512, 0, stream>>>(qh, kh, vt, ab);

  dim3 go(D / 128, NROWS / 64, 1);  // (6, 64)
  gemm_o_kernel<<<go, 256, 0, stream>>>(ab, Mo, bo, out);
}

// Round 8
// 233.025 us; speedup vs baseline: 1.0448x; 1.0448x over previous
//
#include <hip/hip_runtime.h>
#include <math.h>
#include <stdint.h>

// Problem constants
#define D 768
#define S 2048
#define B_ 2
#define NROWS 4096   // B_*S
#define H 12
#define HD 64
#define R_ 16

typedef _Float16 half_t;
typedef _Float16 half8 __attribute__((ext_vector_type(8)));
typedef _Float16 half4 __attribute__((ext_vector_type(4)));
typedef float floatx4 __attribute__((ext_vector_type(4)));

#define MFMA32(a, b, c) __builtin_amdgcn_mfma_f32_16x16x32_f16(a, b, c, 0, 0, 0)
#define MFMA16(a, b, c) __builtin_amdgcn_mfma_f32_16x16x16f16(a, b, c, 0, 0, 0)
#define EXP2F(x) __builtin_amdgcn_exp2f(x)

// global -> LDS async DMA, 16B per lane; lane i lands at base + 16*i.
__device__ __forceinline__ void gl_lds16(const void* gp, half_t* lp) {
  __builtin_amdgcn_global_load_lds(
      (const __attribute__((address_space(1))) void*)(gp),
      (__attribute__((address_space(3))) void*)(lp), 16, 0, 0);
}

// ---------------------------------------------------------------------------
// Fused prep: blocks [0, 9216): fp32->fp16 convert of q,k,v.
//             blocks [9216, 18432): build folded LoRA weights
//             Mh[j][k] = W[j][k] + 4*sum_r A[k,r]A[j,r]  (fp16, [j][k]).
// ---------------------------------------------------------------------------
__global__ __launch_bounds__(256) void prep_kernel(
    const float* __restrict__ q, const float* __restrict__ k,
    const float* __restrict__ v, half_t* __restrict__ xq,
    half_t* __restrict__ xk, half_t* __restrict__ xv,
    const float* __restrict__ Wq, const float* __restrict__ Aq,
    const float* __restrict__ Wk, const float* __restrict__ Ak,
    const float* __restrict__ Wv, const float* __restrict__ Av,
    const float* __restrict__ Wo, half_t* __restrict__ Mq,
    half_t* __restrict__ Mk, half_t* __restrict__ Mv,
    half_t* __restrict__ Mo) {
  const int bid = blockIdx.x;
  if (bid < 9216) {
    const int y = bid / 3072;
    const float* x = (y == 0) ? q : (y == 1) ? k : v;
    half_t* o = (y == 0) ? xq : (y == 1) ? xk : xv;
    int i = (bid - y * 3072) * 1024 + threadIdx.x * 4;
    float4 vv = *reinterpret_cast<const float4*>(x + i);
    half_t tmp[4] = {(half_t)vv.x, (half_t)vv.y, (half_t)vv.z, (half_t)vv.w};
    *reinterpret_cast<uint64_t*>(o + i) = *reinterpret_cast<uint64_t*>(tmp);
  } else {
    const int u = bid - 9216;
    const int y = u / 2304;
    const float* W = (y == 0) ? Wq : (y == 1) ? Wk : (y == 2) ? Wv : Wo;
    const float* A = (y == 0) ? Aq : (y == 1) ? Ak : (y == 2) ? Av : nullptr;
    half_t* M = (y == 0) ? Mq : (y == 1) ? Mk : (y == 2) ? Mv : Mo;
    int idx = (u - y * 2304) * 256 + threadIdx.x;  // j*768 + k
    int j = idx / D;
    int kk = idx - j * D;
    float acc = W[idx];
    if (A != nullptr) {
      float s = 0.f;
#pragma unroll
      for (int r = 0; r < R_; ++r) s += A[kk * R_ + r] * A[j * R_ + r];
      acc += 4.0f * s;
    }
    M[idx] = (half_t)acc;
  }
}

// ---------------------------------------------------------------------------
// QKV GEMM (fp16 in/out): C[n][j] = sum_k X[n][k]*Mh[j][k] + bias[j].
// 64x128 tile, 4 waves (1x4), BK=64, both operands DMA-prefetched,
// double-buffered, one barrier per iter. 48KB LDS -> 3 blocks/CU.
// z==2 writes V output TRANSPOSED per head: vt[(b*H+h)*HD+d][s].
// ---------------------------------------------------------------------------
__global__ __launch_bounds__(256) void gemm_qkv_kernel(
    const half_t* __restrict__ x0, const half_t* __restrict__ x1,
    const half_t* __restrict__ x2, const half_t* __restrict__ m0,
    const half_t* __restrict__ m1, const half_t* __restrict__ m2,
    const float* __restrict__ b0, const float* __restrict__ b1,
    const float* __restrict__ b2, half_t* __restrict__ o0,
    half_t* __restrict__ o1, half_t* __restrict__ o2) {
  constexpr int AG = 8;        // A groups (64 rows x 64 k)
  constexpr int G = AG + 16;   // + B groups (128 cols x 64 k)
  constexpr int PB = G * 512;  // 12288 halfs = 24KB per buffer
  constexpr int TRS = 72;      // V-transpose stride (halfs, %8==0)
  __shared__ __align__(16) half_t smem[2 * PB];  // 48KB

  const int z = blockIdx.z;
  const half_t* X = (z == 0) ? x0 : (z == 1) ? x1 : x2;
  const half_t* M = (z == 0) ? m0 : (z == 1) ? m1 : m2;
  const float* bias = (z == 0) ? b0 : (z == 1) ? b1 : b2;
  half_t* Out = (z == 0) ? o0 : (z == 1) ? o1 : o2;

  const int tid = threadIdx.x;
  const int lane = tid & 63;
  const int wv = tid >> 6;
  const int lr = lane & 15;
  const int lq = lane >> 4;
  const int row0 = blockIdx.y * 64;
  const int j0 = blockIdx.x * 128;
  const int wc = wv;  // 1x4 wave grid

  floatx4 acc[4][2] = {};

#define GSTAGE(bufi, k0)                                                       \
  do {                                                                         \
    _Pragma("unroll") for (int gi = 0; gi < 6; ++gi) {                         \
      int g = wv * 6 + gi;                                                     \
      if (g < AG) {                                                            \
        int t = g >> 1, c = g & 1;                                             \
        gl_lds16(                                                              \
            X + (size_t)(row0 + t * 16 + lr) * D + (k0) + c * 32 + lq * 8,     \
            smem + (bufi)*PB + g * 512);                                       \
      } else {                                                                 \
        int g2 = g - AG;                                                       \
        int u = g2 >> 1, c = g2 & 1;                                           \
        gl_lds16(                                                              \
            M + (size_t)(j0 + u * 16 + lr) * D + (k0) + c * 32 + lq * 8,       \
            smem + (bufi)*PB + AG * 512 + g2 * 512);                           \
      }                                                                        \
    }                                                                          \
  } while (0)

  GSTAGE(0, 0);
  __syncthreads();

  for (int it = 0; it < D / 64; ++it) {
    const int cur = it & 1;
    if (it + 1 < D / 64) GSTAGE(cur ^ 1, (it + 1) * 64);
    const half_t* Ab = smem + cur * PB;
    const half_t* Bb = Ab + AG * 512;
#pragma unroll
    for (int c = 0; c < 2; ++c) {
      half8 af[4], bf[2];
#pragma unroll
      for (int t = 0; t < 4; ++t)
        af[t] = *reinterpret_cast<const half8*>(
            &Ab[((t * 2 + c) * 64 + lane) * 8]);
#pragma unroll
      for (int u = 0; u < 2; ++u)
        bf[u] = *reinterpret_cast<const half8*>(
            &Bb[(((wc * 2 + u) * 2 + c) * 64 + lane) * 8]);
#pragma unroll
      for (int t = 0; t < 4; ++t)
#pragma unroll
        for (int u = 0; u < 2; ++u) acc[t][u] = MFMA32(af[t], bf[u], acc[t][u]);
    }
    __syncthreads();
  }
#undef GSTAGE

  float bv[2];
#pragma unroll
  for (int u = 0; u < 2; ++u) bv[u] = bias[j0 + (wc * 2 + u) * 16 + lr];

  if (z == 2) {
    // transpose through LDS, emit V^T [b][h][d][S] coalesced
#pragma unroll
    for (int t = 0; t < 4; ++t) {
#pragma unroll
      for (int u = 0; u < 2; ++u) {
        int c_local = (wc * 2 + u) * 16 + lr;  // 0..127
#pragma unroll
        for (int r = 0; r < 4; ++r) {
          int r_local = t * 16 + lq * 4 + r;   // 0..63
          smem[c_local * TRS + r_local] = (half_t)(acc[t][u][r] + bv[u]);
        }
      }
    }
    __syncthreads();
    const int bb = row0 >> 11;
    const int s_base = row0 & 2047;
#pragma unroll
    for (int it = 0; it < 4; ++it) {
      int unit = it * 256 + tid;      // 0..1023
      int c_local = unit >> 3;        // channel 0..127
      int chunk = unit & 7;           // token chunk 0..7
      half8 vv =
          *reinterpret_cast<const half8*>(&smem[c_local * TRS + chunk * 8]);
      int gc = j0 + c_local;
      int hh = gc >> 6, dd = gc & 63;
      *reinterpret_cast<half8*>(
          &Out[((size_t)(bb * H + hh) * HD + dd) * S + s_base + chunk * 8]) = vv;
    }
    return;
  }

#pragma unroll
  for (int t = 0; t < 4; ++t) {
#pragma unroll
    for (int u = 0; u < 2; ++u) {
#pragma unroll
      for (int r = 0; r < 4; ++r) {
        int gr = row0 + t * 16 + lq * 4 + r;
        int gc = j0 + (wc * 2 + u) * 16 + lr;
        Out[(size_t)gr * D + gc] = (half_t)(acc[t][u][r] + bv[u]);
      }
    }
  }
}

// ---------------------------------------------------------------------------
// Out-projection GEMM (fp16 in, fp32 out): 64x128 tile, 4 waves (1x4),
// both operands DMA-prefetched, one barrier per iter.
// ---------------------------------------------------------------------------
__global__ __launch_bounds__(256) void gemm_o_kernel(
    const half_t* __restrict__ Xh, const half_t* __restrict__ M,
    const float* __restrict__ bias, float* __restrict__ Out) {
  constexpr int AG = 8;           // A groups (64 rows)
  constexpr int G = AG + 16;      // 24 groups
  constexpr int PB = G * 512;     // halfs per buffer (24KB)
  __shared__ __align__(16) half_t smem[2 * PB];  // 48KB

  const int tid = threadIdx.x;
  const int lane = tid & 63;
  const int wv = tid >> 6;
  const int lr = lane & 15;
  const int lq = lane >> 4;
  const int row0 = blockIdx.y * 64;
  const int j0 = blockIdx.x * 128;
  const int wc = wv;  // 1x4 wave grid

  floatx4 acc[4][2] = {};

#define GSTAGE(bufi, k0)                                                       \
  do {                                                                         \
    _Pragma("unroll") for (int gi = 0; gi < 6; ++gi) {                         \
      int g = wv * 6 + gi;                                                     \
      if (g < AG) {                                                            \
        int t = g >> 1, c = g & 1;                                             \
        gl_lds16(                                                              \
            Xh + (size_t)(row0 + t * 16 + lr) * D + (k0) + c * 32 + lq * 8,    \
            smem + (bufi)*PB + g * 512);                                       \
      } else {                                                                 \
        int g2 = g - AG;                                                       \
        int u = g2 >> 1, c = g2 & 1;                                           \
        gl_lds16(                                                              \
            M + (size_t)(j0 + u * 16 + lr) * D + (k0) + c * 32 + lq * 8,       \
            smem + (bufi)*PB + AG * 512 + g2 * 512);                           \
      }                                                                        \
    }                                                                          \
  } while (0)

  GSTAGE(0, 0);
  __syncthreads();

  for (int it = 0; it < D / 64; ++it) {
    const int cur = it & 1;
    if (it + 1 < D / 64) GSTAGE(cur ^ 1, (it + 1) * 64);
    const half_t* Ab = smem + cur * PB;
    const half_t* Bb = Ab + AG * 512;
#pragma unroll
    for (int c = 0; c < 2; ++c) {
      half8 af[4], bf[2];
#pragma unroll
      for (int t = 0; t < 4; ++t)
        af[t] = *reinterpret_cast<const half8*>(
            &Ab[((t * 2 + c) * 64 + lane) * 8]);
#pragma unroll
      for (int u = 0; u < 2; ++u)
        bf[u] = *reinterpret_cast<const half8*>(
            &Bb[(((wc * 2 + u) * 2 + c) * 64 + lane) * 8]);
#pragma unroll
      for (int t = 0; t < 4; ++t)
#pragma unroll
        for (int u = 0; u < 2; ++u) acc[t][u] = MFMA32(af[t], bf[u], acc[t][u]);
    }
    __syncthreads();
  }
#undef GSTAGE

  float bv[2];
#pragma unroll
  for (int u = 0; u < 2; ++u) bv[u] = bias[j0 + (wc * 2 + u) * 16 + lr];
#pragma unroll
  for (int t = 0; t < 4; ++t) {
#pragma unroll
    for (int u = 0; u < 2; ++u) {
#pragma unroll
      for (int r = 0; r < 4; ++r) {
        int gr = row0 + t * 16 + lq * 4 + r;
        int gc = j0 + (wc * 2 + u) * 16 + lr;
        Out[(size_t)gr * D + gc] = acc[t][u][r] + bv[u];
      }
    }
  }
}

// ---------------------------------------------------------------------------
// Flash attention, in-block split-K. 512 threads (8 waves), 64 q-rows/block.
// Wave w: q-subtile t=w&3 (16 rows), k'-half = w>>2 (2 of 4 u-tiles per iter).
// Partials are additive (no running max) -> merged once at the end via LDS.
//   - S^T = K*Q^T: C-layout == A-frag layout of 16x16x16 -> P in registers.
//   - exp2 (v_exp_f32) with 0.125*log2e folded into Q scale.
//   - l via ones-MFMA: ol[r] = row-sum of P, reg-aligned with o (no shuffles).
// ---------------------------------------------------------------------------
__global__ __launch_bounds__(512, 6) void attn_mfma_kernel(
    const half_t* __restrict__ Qh, const half_t* __restrict__ Kh,
    const half_t* __restrict__ Vt_g, half_t* __restrict__ Oh) {
  __shared__ __align__(16) half_t smem[16384];  // 32KB: Ks[2][4k] Vs[2][4k]
  half_t* Ks = smem;           // [2][8*512]
  half_t* Vs = smem + 8192;    // [2][8*512]

  const int tid = threadIdx.x;
  const int lane = tid & 63;
  const int wv = tid >> 6;       // 0..7
  const int t_ = wv & 3;         // q-subtile
  const int half_ = wv >> 2;     // k'-half
  const int lr = lane & 15;
  const int lq = lane >> 4;
  const int q0 = blockIdx.x * 64;
  const int h = blockIdx.y;
  const int b = blockIdx.z;
  const size_t base = (size_t)b * S * D + h * HD;              // + row*D
  const size_t vtbase = (size_t)(b * H + h) * HD * (size_t)S;  // + d*S + s
  const int qw = q0 + t_ * 16;

  // Q B-fragments, scale = (1/8)*log2(e) -> exp2 later
  const half_t qscale = (half_t)0.18033688f;
  half8 qf[2];
#pragma unroll
  for (int c = 0; c < 2; ++c) {
    half8 qv = *reinterpret_cast<const half8*>(
        &Qh[base + (size_t)(qw + lr) * D + c * 32 + lq * 8]);
#pragma unroll
    for (int j = 0; j < 8; ++j) qv[j] = qv[j] * qscale;
    qf[c] = qv;
  }

  half4 ones;
#pragma unroll
  for (int j = 0; j < 4; ++j) ones[j] = (half_t)1.0f;

  floatx4 o[4] = {};
  floatx4 ol = {};

  // 16 DMA groups (8 K + 8 V), 2 per wave
#define STAGE(bufi, kb)                                                        \
  do {                                                                         \
    _Pragma("unroll") for (int gi = 0; gi < 2; ++gi) {                         \
      int g = wv * 2 + gi;                                                     \
      if (g < 8) {                                                             \
        int u = g >> 1, c = g & 1;                                             \
        gl_lds16(                                                              \
            Kh + base + (size_t)((kb) + u * 16 + lr) * D + c * 32 + lq * 8,    \
            Ks + (bufi)*4096 + g * 512);                                       \
      } else {                                                                 \
        int gv = g - 8;                                                        \
        int ud = gv >> 1, c = gv & 1;                                          \
        gl_lds16(                                                              \
            Vt_g + vtbase + (size_t)(ud * 16 + lr) * S + (kb) + c * 32 +       \
                lq * 8,                                                        \
            Vs + (bufi)*4096 + gv * 512);                                      \
      }                                                                        \
    }                                                                          \
  } while (0)

  STAGE(0, 0);
  __syncthreads();

  for (int it = 0; it < S / 64; ++it) {
    const int cur = it & 1;
    if (it + 1 < S / 64) STAGE(cur ^ 1, (it + 1) * 64);

#pragma unroll
    for (int ui = 0; ui < 2; ++ui) {
      const int u = half_ * 2 + ui;
      half8 kf0 = *reinterpret_cast<const half8*>(
          &Ks[cur * 4096 + ((u * 2 + 0) * 64 + lane) * 8]);
      half8 kf1 = *reinterpret_cast<const half8*>(
          &Ks[cur * 4096 + ((u * 2 + 1) * 64 + lane) * 8]);
      floatx4 st = {};
      st = MFMA32(kf0, qf[0], st);
      st = MFMA32(kf1, qf[1], st);
      half4 pf;
      pf[0] = (half_t)EXP2F(st[0]);
      pf[1] = (half_t)EXP2F(st[1]);
      pf[2] = (half_t)EXP2F(st[2]);
      pf[3] = (half_t)EXP2F(st[3]);
#pragma unroll
      for (int ud = 0; ud < 4; ++ud) {
        half4 vf = *reinterpret_cast<const half4*>(
            &Vs[cur * 4096 + ((ud * 2 + (u >> 1)) * 64 +
                              ((((u & 1) * 2) + (lq >> 1)) * 16 + lr)) *
                                 8 +
                (lq & 1) * 4]);
        o[ud] = MFMA16(pf, vf, o[ud]);
      }
      ol = MFMA16(pf, ones, ol);  // row-sums -> l, reg-aligned with o
    }
    __syncthreads();
  }
#undef STAGE

  // merge k'-halves: waves 4-7 deposit partials (SoA, stride 260), 0-3 reduce
  float* red = (float*)smem;  // 20 comps x 260 floats = 20.8KB <= 32KB
  const int slot = t_ * 64 + lane;  // 0..255
  if (half_ == 1) {
#pragma unroll
    for (int comp = 0; comp < 16; ++comp)
      red[comp * 260 + slot] = o[comp >> 2][comp & 3];
#pragma unroll
    for (int r = 0; r < 4; ++r) red[(16 + r) * 260 + slot] = ol[r];
  }
  __syncthreads();
  if (half_ == 0) {
#pragma unroll
    for (int comp = 0; comp < 16; ++comp)
      o[comp >> 2][comp & 3] += red[comp * 260 + slot];
    float linv[4];
#pragma unroll
    for (int r = 0; r < 4; ++r)
      linv[r] = 1.0f / (ol[r] + red[(16 + r) * 260 + slot]);
#pragma unroll
    for (int ud = 0; ud < 4; ++ud) {
#pragma unroll
      for (int r = 0; r < 4; ++r) {
        int row = qw + lq * 4 + r;
        int col = h * HD + ud * 16 + lr;
        Oh[(size_t)(b * S + row) * D + col] = (half_t)(o[ud][r] * linv[r]);
      }
    }
  }
}

// ---------------------------------------------------------------------------
// Launch
// ---------------------------------------------------------------------------
extern "C" void kernel_launch(void* const* d_in, const int* in_sizes, int n_in,
                              void* d_out, int out_size, void* d_ws,
                              size_t ws_size, hipStream_t stream) {
  const float* query = (const float*)d_in[0];
  const float* key   = (const float*)d_in[1];
  const float* value = (const float*)d_in[2];
  const float* Wq = (const float*)d_in[3];
  const float* bq = (const float*)d_in[4];
  const float* Aq = (const float*)d_in[5];
  const float* Wk = (const float*)d_in[6];
  const float* bk = (const float*)d_in[7];
  const float* Ak = (const float*)d_in[8];
  const float* Wv = (const float*)d_in[9];
  const float* bv = (const float*)d_in[10];
  const float* Av = (const float*)d_in[11];
  const float* Wo = (const float*)d_in[12];
  const float* bo = (const float*)d_in[13];
  float* out = (float*)d_out;

  half_t* hw = (half_t*)d_ws;
  const size_t XSZ = (size_t)NROWS * D;  // 3145728
  const size_t MSZ = (size_t)D * D;      // 589824
  half_t* xq = hw;              // converted inputs (fp16)
  half_t* xk = xq + XSZ;
  half_t* xv = xk + XSZ;
  half_t* qh = xv + XSZ;        // Q projection [n][D]
  half_t* kh = qh + XSZ;        // K projection [n][D]
  half_t* vt = kh + XSZ;        // V projection TRANSPOSED [b][h][d][S]
  half_t* ab = vt + XSZ;        // attention output [n][D]
  half_t* Mq = ab + XSZ;
  half_t* Mk = Mq + MSZ;
  half_t* Mv = Mk + MSZ;
  half_t* Mo = Mv + MSZ;

  prep_kernel<<<18432, 256, 0, stream>>>(query, key, value, xq, xk, xv, Wq, Aq,
                                         Wk, Ak, Wv, Av, Wo, Mq, Mk, Mv, Mo);

  dim3 gq(D / 128, NROWS / 64, 3);  // (6, 64, 3) = 1152 blocks
  gemm_qkv_kernel<<<gq, 256, 0, stream>>>(xq, xk, xv, Mq, Mk, Mv, bq, bk, bv,
                                          qh, kh, vt);

  dim3 ga(S / 64, H, B_);  // (32, 12, 2)
  attn_mfma_kernel<<<ga, 512, 0, stream>>>(qh, kh, vt, ab);

  dim3 go(D / 128, NROWS / 64, 1);  // (6, 64)
  gemm_o_kernel<<<go, 256, 0, stream>>>(ab, Mo, bo, out);
}